// Round 8
// baseline (779.382 us; speedup 1.0000x reference)
//
#include <hip/hip_runtime.h>
#include <hip/hip_bf16.h>

typedef _Float16 f16;
typedef _Float16 half8 __attribute__((ext_vector_type(8)));
typedef _Float16 half4v __attribute__((ext_vector_type(4)));
typedef float f32x4 __attribute__((ext_vector_type(4)));
typedef float f32x16 __attribute__((ext_vector_type(16)));

#define B_ 4
#define S_ 3072
#define D_ 768
#define E_ 2000
#define NEG_INF -1.0e6f

// async global->LDS, 16B per lane; per-lane global src, linear LDS dest
#define GLD16(gsrc, ldst)                                                     \
  __builtin_amdgcn_global_load_lds(                                           \
      (const __attribute__((address_space(1))) void*)(gsrc),                  \
      (__attribute__((address_space(3))) void*)(ldst), 16, 0, 0)

// ---------------------------------------------------------------------------
// h [B,S,D] f32  ->  ht [B,D,S] f16   (LDS-tiled transpose, 64x64)
// ---------------------------------------------------------------------------
__global__ __launch_bounds__(256) void k_transpose(const float* __restrict__ h,
                                                   f16* __restrict__ ht) {
  __shared__ f16 tile[64][65];
  int b = blockIdx.z, s0 = blockIdx.x * 64, d0 = blockIdx.y * 64;
  int t = threadIdx.x, tx = t & 63, ty = t >> 6;
  const float* src = h + ((size_t)b * S_ + s0) * D_ + d0;
#pragma unroll
  for (int i = 0; i < 16; ++i) {
    int sl = i * 4 + ty;
    tile[sl][tx] = (f16)src[(size_t)sl * D_ + tx];
  }
  __syncthreads();
  f16* dst = ht + ((size_t)b * D_ + d0) * S_ + s0;
#pragma unroll
  for (int i = 0; i < 16; ++i) {
    int dl = i * 4 + ty;
    dst[(size_t)dl * S_ + tx] = tile[tx][dl];
  }
}

// ---------------------------------------------------------------------------
// z = tanh(h @ W^T + bias) -> zb f16 [B*S, D]
// ---------------------------------------------------------------------------
__global__ __launch_bounds__(256) void k_zgemm(const float* __restrict__ h,
                                               const float* __restrict__ W,
                                               const float* __restrict__ bias,
                                               f16* __restrict__ zb) {
  __shared__ f16 As[64][40];
  __shared__ f16 Bs[64][40];
  int i0 = blockIdx.x * 64, j0 = blockIdx.y * 64;
  int t = threadIdx.x, w = t >> 6, lane = t & 63, g = lane >> 4, li = lane & 15;
  int wi = w >> 1, wj = w & 1;

  f32x4 acc[2][2];
#pragma unroll
  for (int a = 0; a < 2; ++a)
#pragma unroll
    for (int b2 = 0; b2 < 2; ++b2) acc[a][b2] = (f32x4){0.f, 0.f, 0.f, 0.f};

  int srow = t >> 2, scol = (t & 3) * 8;
  const float* pA = h + (size_t)(i0 + srow) * D_ + scol;
  const float* pB = W + (size_t)(j0 + srow) * D_ + scol;

  for (int kc = 0; kc < D_; kc += 32) {
    float4 a0 = *(const float4*)(pA + kc);
    float4 a1 = *(const float4*)(pA + kc + 4);
    float4 b0 = *(const float4*)(pB + kc);
    float4 b1 = *(const float4*)(pB + kc + 4);
    half8 av = {(f16)a0.x, (f16)a0.y, (f16)a0.z, (f16)a0.w,
                (f16)a1.x, (f16)a1.y, (f16)a1.z, (f16)a1.w};
    half8 bv = {(f16)b0.x, (f16)b0.y, (f16)b0.z, (f16)b0.w,
                (f16)b1.x, (f16)b1.y, (f16)b1.z, (f16)b1.w};
    *(half8*)&As[srow][scol] = av;
    *(half8*)&Bs[srow][scol] = bv;
    __syncthreads();
#pragma unroll
    for (int it = 0; it < 2; ++it) {
      half8 af = *(const half8*)&As[wi * 32 + it * 16 + li][g * 8];
#pragma unroll
      for (int jt = 0; jt < 2; ++jt) {
        half8 bf = *(const half8*)&Bs[wj * 32 + jt * 16 + li][g * 8];
        acc[it][jt] =
            __builtin_amdgcn_mfma_f32_16x16x32_f16(af, bf, acc[it][jt], 0, 0, 0);
      }
    }
    __syncthreads();
  }
#pragma unroll
  for (int it = 0; it < 2; ++it) {
#pragma unroll
    for (int jt = 0; jt < 2; ++jt) {
      int jj = j0 + wj * 32 + jt * 16 + li;
      float bsv = bias[jj];
#pragma unroll
      for (int r = 0; r < 4; ++r) {
        int ii = i0 + wi * 32 + it * 16 + g * 4 + r;
        float v = acc[it][jt][r] + bsv;
        zb[(size_t)ii * D_ + jj] = (f16)tanhf(v);
      }
    }
  }
}

// ---------------------------------------------------------------------------
// Fused flash attention + head max-pool, v8: 32x32x16 MFMA everywhere.
// 8 waves, 64 q, 32-key tiles, 3 raw-barrier segments, counted vmcnt.
// QK roles: (qh 0..1, kq 0..3) 4-way k-split; C[s][q], lane owns col q.
// Softmax: kq0 waves, fully in-register per lane (1 shfl_xor(32)).
// PV roles: dh = w (96-d slice), A = P from LDS, B = V from LDS (read-once).
// Cp exchange in f16; Pt aliases Cp slots 4-5; Msk aliases Lfin. 160,256 B.
// ---------------------------------------------------------------------------
__global__ __launch_bounds__(512)
__attribute__((amdgpu_waves_per_eu(2, 2)))
void k_attn(const float* __restrict__ lf,
            const f16* __restrict__ zb,
            const f16* __restrict__ ht,
            const int* __restrict__ amask,
            float* __restrict__ out_m) {
  __shared__ __align__(16) char Lds[160256];
  char* KsB = Lds;                          // 2 x 49152, rows 1536B, swz (s&7)<<4
  char* VsB = Lds + 98304;                  // 49152: [768 d][32 s], swz ((d>>1)&3)<<4
  char* CpB = Lds + 147456;                 // 6 x 2048 f16 partial slots
  char* PtB = CpB + 8192;                   // 4096 = slots 4,5 (aliased, audited)
  float* FacB = (float*)(Lds + 159744);     // 256
  int* MskI = (int*)(Lds + 160000);         // 128 (aliases Lfin; Msk dead by then)
  float* LfinB = (float*)(Lds + 160000);    // 256

  // ---- XCD-grouping swizzle (grid = 512 flat, 12 dead blocks)
  const int fid = blockIdx.x;
  const int x2 = fid & 7, u = fid >> 3;
  const int b = x2 >> 1;
  const int qtile = (x2 & 1) * 64 + u;
  if (qtile >= 125) return;
  const int q0 = qtile * 64;
  const int e0 = qtile * 16;

  const int t = threadIdx.x, w = t >> 6, l = t & 63;
  const int l31 = l & 31, h = l >> 5, h16 = h * 16;
  const int qh = w & 1, kq = w >> 1;  // QK/softmax roles
  const int dh = w;                   // PV role: 96-d slice

  // ---- Q fragments (B operand): q = q0+qh*32+l31, k = kq*192+kf*16+h*8
  half8 qf[12];
  {
    const float* qp = lf + (size_t)(q0 + qh * 32 + l31) * D_ + kq * 192 + h * 8;
#pragma unroll
    for (int kf = 0; kf < 12; ++kf) {
      float4 v0 = *(const float4*)(qp + kf * 16);
      float4 v1 = *(const float4*)(qp + kf * 16 + 4);
      qf[kf] = (half8){(f16)v0.x, (f16)v0.y, (f16)v0.z, (f16)v0.w,
                       (f16)v1.x, (f16)v1.y, (f16)v1.z, (f16)v1.w};
    }
  }

  // ---- K staging: LDS linear dest, global source pre-swizzled
  int klds[6], kgsw[6];
#pragma unroll
  for (int k = 0; k < 6; ++k) {
    int lin = (w * 6 + k) * 1024 + l * 16;
    int row = lin / 1536;
    int xo = lin - row * 1536;
    klds[k] = lin;
    kgsw[k] = row * 1536 + (xo ^ ((row & 7) << 4));
  }
  // ---- V staging: Vs[d][32 s] rows 64 B, swizzle ((d>>1)&3)<<4
  int vlds[6], vgsw[6];
#pragma unroll
  for (int k = 0; k < 6; ++k) {
    int j = w * 6 + k;
    int vd = j * 16 + (l >> 2);
    vlds[k] = j * 1024 + l * 16;
    vgsw[k] = vd * (S_ * 2) + (((l & 3) * 16) ^ (((vd >> 1) & 3) << 4));
  }

  // ---- QK A(K)-frag base: s-row = l31, k = kq*192 + kf*16 + h*8
  const int am7 = (l & 7) << 4;
  const int abase = l31 * 1536 + kq * 384;

  // ---- row-swizzle for 64B-row buffers (Pt, Cp, Vs): ((row>>1)&3)<<4
  const int rswz = ((l31 >> 1) & 3) << 4;
  const int cqoff = l31 * 64;
  const int csl = (kq >= 1) ? ((kq - 1) * 2 + qh) : 0;

  const char* zbB = (const char*)zb + (size_t)b * S_ * 1536;
  const char* htB = (const char*)ht + (size_t)b * D_ * S_ * 2;

  // ---- prologue: DMA K(0) into buf 0
#pragma unroll
  for (int k = 0; k < 6; ++k) GLD16(zbB + kgsw[k], KsB + klds[k]);
  asm volatile("s_waitcnt vmcnt(0)" ::: "memory");
  __syncthreads();

  float mreg = -3.0e38f, lreg = 0.0f;
  f32x16 oacc[2][3];
#pragma unroll
  for (int a = 0; a < 2; ++a)
#pragma unroll
    for (int d = 0; d < 3; ++d)
#pragma unroll
      for (int j = 0; j < 16; ++j) oacc[a][d][j] = 0.f;

  for (int i = 0; i < 96; ++i) {
    const int s0 = i * 32;
    const int s0n = (i < 95) ? s0 + 32 : 0;
    const char* ksC = KsB + (i & 1) * 49152;
    char* ksN = KsB + ((i & 1) ^ 1) * 49152;

    // ================= seg1 =================
    int mcur = (t < 32) ? amask[b * S_ + s0 + t] : 0;
    // V(i) DMA
    {
      const char* src = htB + (size_t)s0 * 2;
#pragma unroll
      for (int k = 0; k < 6; ++k) GLD16(src + vgsw[k], VsB + vlds[k]);
    }
    // QK(i): C[s][q] 32x32, 2 chains
    f32x16 ca, cb2;
#pragma unroll
    for (int j = 0; j < 16; ++j) { ca[j] = 0.f; cb2[j] = 0.f; }
    __builtin_amdgcn_s_setprio(1);
#pragma unroll
    for (int kf = 0; kf < 6; ++kf) {
      half8 a = *(const half8*)(ksC + abase + ((kf * 32 + h16) ^ am7));
      ca = __builtin_amdgcn_mfma_f32_32x32x16_f16(a, qf[kf], ca, 0, 0, 0);
    }
#pragma unroll
    for (int kf = 6; kf < 12; ++kf) {
      half8 a = *(const half8*)(ksC + abase + ((kf * 32 + h16) ^ am7));
      cb2 = __builtin_amdgcn_mfma_f32_32x32x16_f16(a, qf[kf], cb2, 0, 0, 0);
    }
    __builtin_amdgcn_s_setprio(0);
#pragma unroll
    for (int j = 0; j < 16; ++j) ca[j] += cb2[j];

    // K(i+1) DMA
    __builtin_amdgcn_sched_barrier(0);
    {
      const char* src = zbB + (size_t)s0n * 1536;
#pragma unroll
      for (int k = 0; k < 6; ++k) GLD16(src + kgsw[k], ksN + klds[k]);
    }
    // Cp write (kq != 0): f16-packed partials, 4 x b64
    if (kq != 0) {
      char* cp = CpB + csl * 2048 + cqoff;
#pragma unroll
      for (int rr = 0; rr < 4; ++rr) {
        half4v pk = {(f16)ca[4 * rr], (f16)ca[4 * rr + 1], (f16)ca[4 * rr + 2],
                     (f16)ca[4 * rr + 3]};
        *(half4v*)(cp + ((rr * 16 + h * 8) ^ rswz)) = pk;
      }
    }
    asm volatile("s_waitcnt vmcnt(12)" ::: "memory");  // mask landed (wave0)
    if (t < 32) MskI[t] = mcur;
    asm volatile("s_waitcnt lgkmcnt(0)" ::: "memory");
    __builtin_amdgcn_s_barrier();  // bar B

    // ================= seg2 =================
    if (kq == 0) {
      // combine 3 partials
#pragma unroll
      for (int kk = 1; kk < 4; ++kk) {
        const char* sp = CpB + ((kk - 1) * 2 + qh) * 2048 + cqoff;
#pragma unroll
        for (int rr = 0; rr < 4; ++rr) {
          half4v pk = *(const half4v*)(sp + ((rr * 16 + h * 8) ^ rswz));
          ca[4 * rr + 0] += (float)pk[0];
          ca[4 * rr + 1] += (float)pk[1];
          ca[4 * rr + 2] += (float)pk[2];
          ca[4 * rr + 3] += (float)pk[3];
        }
      }
      // mask + max (lane owns q = qh*32 + l31; 16 s-values in regs)
      float p[16];
      float vmax = -3.0e38f;
#pragma unroll
      for (int rr = 0; rr < 4; ++rr) {
        int4 m4 = *(const int4*)(MskI + rr * 8 + h * 4);
#pragma unroll
        for (int j = 0; j < 4; ++j) {
          float sv = ca[4 * rr + j];
          if (!((&m4.x)[j])) sv = NEG_INF;
          p[4 * rr + j] = sv;
          vmax = fmaxf(vmax, sv);
        }
      }
      vmax = fmaxf(vmax, __shfl_xor(vmax, 32));
      float Mn = fmaxf(mreg, vmax);
      float fec = __expf(mreg - Mn);
      mreg = Mn;
      float ts = 0.f;
#pragma unroll
      for (int j = 0; j < 16; ++j) {
        p[j] = __expf(p[j] - Mn);
        ts += p[j];
      }
      ts += __shfl_xor(ts, 32);
      lreg = lreg * fec + ts;
      if (l < 32) FacB[qh * 32 + l] = fec;
      // P write (over own Cp slot 4+qh — reads above already done)
      char* pw = PtB + qh * 2048 + cqoff;
#pragma unroll
      for (int rr = 0; rr < 4; ++rr) {
        half4v pk = {(f16)p[4 * rr], (f16)p[4 * rr + 1], (f16)p[4 * rr + 2],
                     (f16)p[4 * rr + 3]};
        *(half4v*)(pw + ((rr * 16 + h * 8) ^ rswz)) = pk;
      }
    }
    // V(i) drained; 6 K(i+1) DMAs stay in flight
    asm volatile("s_waitcnt vmcnt(6) lgkmcnt(0)" ::: "memory");
    __builtin_amdgcn_s_barrier();  // bar C

    // ================= seg3 =================
    {
      f32x4 frv[2][4];
#pragma unroll
      for (int q2 = 0; q2 < 2; ++q2)
#pragma unroll
        for (int rr = 0; rr < 4; ++rr)
          frv[q2][rr] = *(const f32x4*)(FacB + q2 * 32 + rr * 8 + h * 4);
#pragma unroll
      for (int q2 = 0; q2 < 2; ++q2)
#pragma unroll
        for (int dt = 0; dt < 3; ++dt)
#pragma unroll
          for (int j = 0; j < 16; ++j)
            oacc[q2][dt][j] *= frv[q2][j >> 2][j & 3];
      half8 pa[2][2];
#pragma unroll
      for (int q2 = 0; q2 < 2; ++q2)
#pragma unroll
        for (int ss = 0; ss < 2; ++ss)
          pa[q2][ss] = *(const half8*)(PtB + q2 * 2048 + cqoff +
                                       ((ss * 32 + h16) ^ rswz));
      __builtin_amdgcn_s_setprio(1);
#pragma unroll
      for (int dt = 0; dt < 3; ++dt)
#pragma unroll
        for (int ss = 0; ss < 2; ++ss) {
          half8 vb = *(const half8*)(VsB + (dh * 96 + dt * 32 + l31) * 64 +
                                     ((ss * 32 + h16) ^ rswz));
#pragma unroll
          for (int q2 = 0; q2 < 2; ++q2)
            oacc[q2][dt] = __builtin_amdgcn_mfma_f32_32x32x16_f16(
                pa[q2][ss], vb, oacc[q2][dt], 0, 0, 0);
        }
      __builtin_amdgcn_s_setprio(0);
    }
    asm volatile("s_waitcnt vmcnt(0)" ::: "memory");  // K(i+1) landed
    __builtin_amdgcn_s_barrier();  // bar D
  }

  if (kq == 0 && l < 32) LfinB[qh * 32 + l] = lreg;
  __syncthreads();

  // ---- epilogue: O/l, head max-pool (head = reg&3), store ----
  f32x4 rlv[2][4];
#pragma unroll
  for (int q2 = 0; q2 < 2; ++q2)
#pragma unroll
    for (int rr = 0; rr < 4; ++rr) {
      f32x4 lv = *(const f32x4*)(LfinB + q2 * 32 + rr * 8 + h * 4);
      rlv[q2][rr] =
          (f32x4){1.0f / lv[0], 1.0f / lv[1], 1.0f / lv[2], 1.0f / lv[3]};
    }
#pragma unroll
  for (int q2 = 0; q2 < 2; ++q2)
#pragma unroll
    for (int dt = 0; dt < 3; ++dt)
#pragma unroll
      for (int rr = 0; rr < 4; ++rr) {
        float mv = oacc[q2][dt][4 * rr + 0] * rlv[q2][rr][0];
        mv = fmaxf(mv, oacc[q2][dt][4 * rr + 1] * rlv[q2][rr][1]);
        mv = fmaxf(mv, oacc[q2][dt][4 * rr + 2] * rlv[q2][rr][2]);
        mv = fmaxf(mv, oacc[q2][dt][4 * rr + 3] * rlv[q2][rr][3]);
        int e_loc = q2 * 8 + rr * 2 + h;
        out_m[((size_t)b * E_ + e0 + e_loc) * D_ + dh * 96 + dt * 32 + l31] = mv;
      }
}

// ---------------------------------------------------------------------------
// logits[b,e] = sum_d cls_w[e,d]*m[b,e,d] + cls_b[e]; one wave per (b,e)
// ---------------------------------------------------------------------------
__global__ __launch_bounds__(256) void k_logits(const float* __restrict__ cw,
                                                const float* __restrict__ cb,
                                                const float* __restrict__ m,
                                                float* __restrict__ out) {
  int t = threadIdx.x, w = t >> 6, lane = t & 63;
  int rid = blockIdx.x * 4 + w;  // 0..7999
  int b = rid / E_, e = rid - b * E_;
  const float* mr = m + (size_t)rid * D_;
  const float* cr = cw + (size_t)e * D_;
  float acc = 0.f;
#pragma unroll
  for (int i = 0; i < 12; ++i) acc += cr[i * 64 + lane] * mr[i * 64 + lane];
#pragma unroll
  for (int off = 32; off >= 1; off >>= 1) acc += __shfl_xor(acc, off);
  if (lane == 0) out[rid] = acc + cb[e];
}

// ---------------------------------------------------------------------------
extern "C" void kernel_launch(void* const* d_in, const int* in_sizes, int n_in,
                              void* d_out, int out_size, void* d_ws, size_t ws_size,
                              hipStream_t stream) {
  const float* h = (const float*)d_in[0];
  const int* amask = (const int*)d_in[1];
  const float* lf = (const float*)d_in[2];
  const float* Ww = (const float*)d_in[3];
  const float* Wb = (const float*)d_in[4];
  const float* cw = (const float*)d_in[5];
  const float* cb = (const float*)d_in[6];
  float* out = (float*)d_out;

  f16* zb = (f16*)d_ws;                     // 12288*768*2 = 18874368 B
  f16* ht = (f16*)((char*)d_ws + 18874368); // 4*768*3072*2 = 18874368 B

  k_transpose<<<dim3(48, 12, 4), 256, 0, stream>>>(h, ht);
  k_zgemm<<<dim3(192, 12), 256, 0, stream>>>(h, Ww, Wb, zb);
  k_attn<<<512, 512, 0, stream>>>(lf, zb, ht, amask, out + 8000);
  k_logits<<<2000, 256, 0, stream>>>(cw, cb, out + 8000, out);
}

// Round 9
// 614.934 us; speedup vs baseline: 1.2674x; 1.2674x over previous
//
#include <hip/hip_runtime.h>
#include <hip/hip_bf16.h>

typedef _Float16 f16;
typedef _Float16 half8 __attribute__((ext_vector_type(8)));
typedef _Float16 half4v __attribute__((ext_vector_type(4)));
typedef float f32x4 __attribute__((ext_vector_type(4)));
typedef float f32x16 __attribute__((ext_vector_type(16)));

#define B_ 4
#define S_ 3072
#define D_ 768
#define E_ 2000
#define NEG_INF -1.0e6f

// async global->LDS, 16B per lane; per-lane global src, linear LDS dest
#define GLD16(gsrc, ldst)                                                     \
  __builtin_amdgcn_global_load_lds(                                           \
      (const __attribute__((address_space(1))) void*)(gsrc),                  \
      (__attribute__((address_space(3))) void*)(ldst), 16, 0, 0)

// ---------------------------------------------------------------------------
// h [B,S,D] f32  ->  ht [B,D,S] f16   (LDS-tiled transpose, 64x64)
// ---------------------------------------------------------------------------
__global__ __launch_bounds__(256) void k_transpose(const float* __restrict__ h,
                                                   f16* __restrict__ ht) {
  __shared__ f16 tile[64][65];
  int b = blockIdx.z, s0 = blockIdx.x * 64, d0 = blockIdx.y * 64;
  int t = threadIdx.x, tx = t & 63, ty = t >> 6;
  const float* src = h + ((size_t)b * S_ + s0) * D_ + d0;
#pragma unroll
  for (int i = 0; i < 16; ++i) {
    int sl = i * 4 + ty;
    tile[sl][tx] = (f16)src[(size_t)sl * D_ + tx];
  }
  __syncthreads();
  f16* dst = ht + ((size_t)b * D_ + d0) * S_ + s0;
#pragma unroll
  for (int i = 0; i < 16; ++i) {
    int dl = i * 4 + ty;
    dst[(size_t)dl * S_ + tx] = tile[tx][dl];
  }
}

// ---------------------------------------------------------------------------
// z = tanh(h @ W^T + bias) -> zb f16 [B*S, D]
// ---------------------------------------------------------------------------
__global__ __launch_bounds__(256) void k_zgemm(const float* __restrict__ h,
                                               const float* __restrict__ W,
                                               const float* __restrict__ bias,
                                               f16* __restrict__ zb) {
  __shared__ f16 As[64][40];
  __shared__ f16 Bs[64][40];
  int i0 = blockIdx.x * 64, j0 = blockIdx.y * 64;
  int t = threadIdx.x, w = t >> 6, lane = t & 63, g = lane >> 4, li = lane & 15;
  int wi = w >> 1, wj = w & 1;

  f32x4 acc[2][2];
#pragma unroll
  for (int a = 0; a < 2; ++a)
#pragma unroll
    for (int b2 = 0; b2 < 2; ++b2) acc[a][b2] = (f32x4){0.f, 0.f, 0.f, 0.f};

  int srow = t >> 2, scol = (t & 3) * 8;
  const float* pA = h + (size_t)(i0 + srow) * D_ + scol;
  const float* pB = W + (size_t)(j0 + srow) * D_ + scol;

  for (int kc = 0; kc < D_; kc += 32) {
    float4 a0 = *(const float4*)(pA + kc);
    float4 a1 = *(const float4*)(pA + kc + 4);
    float4 b0 = *(const float4*)(pB + kc);
    float4 b1 = *(const float4*)(pB + kc + 4);
    half8 av = {(f16)a0.x, (f16)a0.y, (f16)a0.z, (f16)a0.w,
                (f16)a1.x, (f16)a1.y, (f16)a1.z, (f16)a1.w};
    half8 bv = {(f16)b0.x, (f16)b0.y, (f16)b0.z, (f16)b0.w,
                (f16)b1.x, (f16)b1.y, (f16)b1.z, (f16)b1.w};
    *(half8*)&As[srow][scol] = av;
    *(half8*)&Bs[srow][scol] = bv;
    __syncthreads();
#pragma unroll
    for (int it = 0; it < 2; ++it) {
      half8 af = *(const half8*)&As[wi * 32 + it * 16 + li][g * 8];
#pragma unroll
      for (int jt = 0; jt < 2; ++jt) {
        half8 bf = *(const half8*)&Bs[wj * 32 + jt * 16 + li][g * 8];
        acc[it][jt] =
            __builtin_amdgcn_mfma_f32_16x16x32_f16(af, bf, acc[it][jt], 0, 0, 0);
      }
    }
    __syncthreads();
  }
#pragma unroll
  for (int it = 0; it < 2; ++it) {
#pragma unroll
    for (int jt = 0; jt < 2; ++jt) {
      int jj = j0 + wj * 32 + jt * 16 + li;
      float bsv = bias[jj];
#pragma unroll
      for (int r = 0; r < 4; ++r) {
        int ii = i0 + wi * 32 + it * 16 + g * 4 + r;
        float v = acc[it][jt][r] + bsv;
        zb[(size_t)ii * D_ + jj] = (f16)tanhf(v);
      }
    }
  }
}

// ---------------------------------------------------------------------------
// Fused flash attention + head max-pool, v9: 2 blocks/CU.
// LDS 66,304 B (K single-buffer 48K + Cp 12K + Pt 4K + misc) -> 2 blocks/CU,
// 500 blocks all co-resident; cross-block TLP hides latency.
// 8 waves, 64 q, 32-key tiles, 2 raw barriers/iter:
//  seg1: PV(i-1){Fac rescale, Pt LDS, V regs} | issue V(i)->regs |
//        QK(i){Ks} | Cp write | lgkmcnt(0) barrier B
//  seg2: K(i+1) DMA -> Ks (post-B safe) | kq0 softmax (exp in-place) ->
//        Pt/Fac | Msk[(i+1)&1] | vmcnt(0) lgkmcnt(0) barrier C
// V is per-wave-private (d-split) -> 24 VGPR single buffer, no LDS.
// ---------------------------------------------------------------------------
__global__ __launch_bounds__(512)
void k_attn(const float* __restrict__ lf,
            const f16* __restrict__ zb,
            const f16* __restrict__ ht,
            const int* __restrict__ amask,
            float* __restrict__ out_m) {
  __shared__ __align__(16) char Lds[66304];
  char* KsB = Lds;                        // 49152: 32 rows x 1536 B, swz (r&7)<<4
  char* CpB = Lds + 49152;                // 6 x 2048 f16 partial slots
  char* PtB = Lds + 61440;                // 2 x 2048
  float* FacB = (float*)(Lds + 65536);    // 256
  float* LfinB = (float*)(Lds + 65792);   // 256
  int* MskI = (int*)(Lds + 66048);        // 2 x 32 ints

  // ---- XCD-grouping swizzle (grid = 512 flat, 12 dead blocks)
  const int fid = blockIdx.x;
  const int x2 = fid & 7, u = fid >> 3;
  const int b = x2 >> 1;
  const int qtile = (x2 & 1) * 64 + u;
  if (qtile >= 125) return;
  const int q0 = qtile * 64;
  const int e0 = qtile * 16;

  const int t = threadIdx.x, w = t >> 6, l = t & 63;
  const int l31 = l & 31, h = l >> 5, h16 = h * 16;
  const int qh = w & 1, kq = w >> 1;  // QK/softmax roles
  const int dh = w;                   // PV role: 96-d slice

  // ---- Q fragments (B operand): q = q0+qh*32+l31, k = kq*192+kf*16+h*8
  half8 qf[12];
  {
    const float* qp = lf + (size_t)(q0 + qh * 32 + l31) * D_ + kq * 192 + h * 8;
#pragma unroll
    for (int kf = 0; kf < 12; ++kf) {
      float4 v0 = *(const float4*)(qp + kf * 16);
      float4 v1 = *(const float4*)(qp + kf * 16 + 4);
      qf[kf] = (half8){(f16)v0.x, (f16)v0.y, (f16)v0.z, (f16)v0.w,
                       (f16)v1.x, (f16)v1.y, (f16)v1.z, (f16)v1.w};
    }
  }

  // ---- K staging: LDS linear dest, global source pre-swizzled
  int klds[6], kgsw[6];
#pragma unroll
  for (int k = 0; k < 6; ++k) {
    int lin = (w * 6 + k) * 1024 + l * 16;
    int row = lin / 1536;
    int xo = lin - row * 1536;
    klds[k] = lin;
    kgsw[k] = row * 1536 + (xo ^ ((row & 7) << 4));
  }

  // ---- QK A(K)-frag base: s-row = l31, k = kq*192 + kf*16 + h*8
  const int am7 = (l & 7) << 4;
  const int abase = l31 * 1536 + kq * 384;

  // ---- row-swizzle for 64B-row buffers (Pt, Cp): ((row>>1)&3)<<4
  const int rswz = ((l31 >> 1) & 3) << 4;
  const int cqoff = l31 * 64;
  const int csl = (kq >= 1) ? ((kq - 1) * 2 + qh) : 0;

  const char* zbB = (const char*)zb + (size_t)b * S_ * 1536;
  const f16* vbase = ht + ((size_t)b * D_ + dh * 96 + l31) * S_ + h * 8;

  // ---- prologue: DMA K(0), mask(0)
#pragma unroll
  for (int k = 0; k < 6; ++k) GLD16(zbB + kgsw[k], KsB + klds[k]);
  if (t < 32) MskI[t] = amask[b * S_ + t];
  asm volatile("s_waitcnt vmcnt(0)" ::: "memory");
  __syncthreads();

  float mreg = -3.0e38f, lreg = 0.0f;
  f32x16 oacc[2][3];
#pragma unroll
  for (int a = 0; a < 2; ++a)
#pragma unroll
    for (int d = 0; d < 3; ++d)
#pragma unroll
      for (int j = 0; j < 16; ++j) oacc[a][d][j] = 0.f;

  half8 Vb[6];  // per-wave V slice, single-buffered across iterations

  for (int i = 0; i < 96; ++i) {
    const int s0 = i * 32;
    const int s0n = (i < 95) ? s0 + 32 : 0;

    // ================= seg1 =================
    int mnext = (t < 32) ? amask[b * S_ + s0n + t] : 0;

    // PV(i-1): rescale + MFMA (P from LDS, V from regs)
    if (i > 0) {
      f32x4 frv[2][4];
#pragma unroll
      for (int q2 = 0; q2 < 2; ++q2)
#pragma unroll
        for (int rr = 0; rr < 4; ++rr)
          frv[q2][rr] = *(const f32x4*)(FacB + q2 * 32 + rr * 8 + h * 4);
#pragma unroll
      for (int q2 = 0; q2 < 2; ++q2)
#pragma unroll
        for (int dt = 0; dt < 3; ++dt)
#pragma unroll
          for (int j = 0; j < 16; ++j)
            oacc[q2][dt][j] *= frv[q2][j >> 2][j & 3];
      half8 pa[2][2];
#pragma unroll
      for (int q2 = 0; q2 < 2; ++q2)
#pragma unroll
        for (int ss = 0; ss < 2; ++ss)
          pa[q2][ss] = *(const half8*)(PtB + q2 * 2048 + cqoff +
                                       ((ss * 32 + h16) ^ rswz));
      __builtin_amdgcn_s_setprio(1);
#pragma unroll
      for (int dt = 0; dt < 3; ++dt)
#pragma unroll
        for (int ss = 0; ss < 2; ++ss)
#pragma unroll
          for (int q2 = 0; q2 < 2; ++q2)
            oacc[q2][dt] = __builtin_amdgcn_mfma_f32_32x32x16_f16(
                pa[q2][ss], Vb[dt * 2 + ss], oacc[q2][dt], 0, 0, 0);
      __builtin_amdgcn_s_setprio(0);
    }

    // issue V(i) -> regs (WAR on Vb keeps this after PV(i-1))
    {
      const f16* vp = vbase + s0;
#pragma unroll
      for (int dt = 0; dt < 3; ++dt)
#pragma unroll
        for (int ss = 0; ss < 2; ++ss)
          Vb[dt * 2 + ss] = *(const half8*)(vp + (size_t)dt * 32 * S_ + ss * 16);
    }

    // QK(i): C[s][q] 32x32, single chain
    f32x16 ca;
#pragma unroll
    for (int j = 0; j < 16; ++j) ca[j] = 0.f;
    __builtin_amdgcn_s_setprio(1);
#pragma unroll
    for (int kf = 0; kf < 12; ++kf) {
      half8 a = *(const half8*)(KsB + abase + ((kf * 32 + h16) ^ am7));
      ca = __builtin_amdgcn_mfma_f32_32x32x16_f16(a, qf[kf], ca, 0, 0, 0);
    }
    __builtin_amdgcn_s_setprio(0);

    // Cp write (kq != 0): f16-packed partials, 4 x b64
    if (kq != 0) {
      char* cp = CpB + csl * 2048 + cqoff;
#pragma unroll
      for (int rr = 0; rr < 4; ++rr) {
        half4v pk = {(f16)ca[4 * rr], (f16)ca[4 * rr + 1], (f16)ca[4 * rr + 2],
                     (f16)ca[4 * rr + 3]};
        *(half4v*)(cp + ((rr * 16 + h * 8) ^ rswz)) = pk;
      }
    }
    asm volatile("s_waitcnt lgkmcnt(0)" ::: "memory");
    __builtin_amdgcn_s_barrier();  // bar B: Cp ready, QK reads of Ks done

    // ================= seg2 =================
    // K(i+1) DMA into (single) Ks — safe after bar B
    {
      const char* src = zbB + (size_t)s0n * 1536;
#pragma unroll
      for (int k = 0; k < 6; ++k) GLD16(src + kgsw[k], KsB + klds[k]);
    }
    if (kq == 0) {
      // combine 3 partials
#pragma unroll
      for (int kk = 1; kk < 4; ++kk) {
        const char* sp = CpB + ((kk - 1) * 2 + qh) * 2048 + cqoff;
#pragma unroll
        for (int rr = 0; rr < 4; ++rr) {
          half4v pk = *(const half4v*)(sp + ((rr * 16 + h * 8) ^ rswz));
          ca[4 * rr + 0] += (float)pk[0];
          ca[4 * rr + 1] += (float)pk[1];
          ca[4 * rr + 2] += (float)pk[2];
          ca[4 * rr + 3] += (float)pk[3];
        }
      }
      // mask + max (lane owns q = qh*32 + l31; 16 s-values in regs)
      const int* mk = MskI + (i & 1) * 32;
      float vmax = -3.0e38f;
#pragma unroll
      for (int rr = 0; rr < 4; ++rr) {
        int4 m4 = *(const int4*)(mk + rr * 8 + h * 4);
#pragma unroll
        for (int j = 0; j < 4; ++j) {
          float sv = ca[4 * rr + j];
          if (!((&m4.x)[j])) sv = NEG_INF;
          ca[4 * rr + j] = sv;
          vmax = fmaxf(vmax, sv);
        }
      }
      vmax = fmaxf(vmax, __shfl_xor(vmax, 32));
      float Mn = fmaxf(mreg, vmax);
      float fec = __expf(mreg - Mn);
      mreg = Mn;
      float ts = 0.f;
#pragma unroll
      for (int j = 0; j < 16; ++j) {
        ca[j] = __expf(ca[j] - Mn);
        ts += ca[j];
      }
      ts += __shfl_xor(ts, 32);
      lreg = lreg * fec + ts;
      if (l < 32) FacB[qh * 32 + l] = fec;
      char* pw = PtB + qh * 2048 + cqoff;
#pragma unroll
      for (int rr = 0; rr < 4; ++rr) {
        half4v pk = {(f16)ca[4 * rr], (f16)ca[4 * rr + 1], (f16)ca[4 * rr + 2],
                     (f16)ca[4 * rr + 3]};
        *(half4v*)(pw + ((rr * 16 + h * 8) ^ rswz)) = pk;
      }
    }
    if (t < 32) MskI[((i + 1) & 1) * 32 + t] = mnext;
    asm volatile("s_waitcnt vmcnt(0) lgkmcnt(0)" ::: "memory");
    __builtin_amdgcn_s_barrier();  // bar C: Ks(i+1)/Pt/Fac/Msk ready
  }

  // ---- final PV (tile 95) ----
  {
    f32x4 frv[2][4];
#pragma unroll
    for (int q2 = 0; q2 < 2; ++q2)
#pragma unroll
      for (int rr = 0; rr < 4; ++rr)
        frv[q2][rr] = *(const f32x4*)(FacB + q2 * 32 + rr * 8 + h * 4);
#pragma unroll
    for (int q2 = 0; q2 < 2; ++q2)
#pragma unroll
      for (int dt = 0; dt < 3; ++dt)
#pragma unroll
        for (int j = 0; j < 16; ++j)
          oacc[q2][dt][j] *= frv[q2][j >> 2][j & 3];
    half8 pa[2][2];
#pragma unroll
    for (int q2 = 0; q2 < 2; ++q2)
#pragma unroll
      for (int ss = 0; ss < 2; ++ss)
        pa[q2][ss] = *(const half8*)(PtB + q2 * 2048 + cqoff +
                                     ((ss * 32 + h16) ^ rswz));
#pragma unroll
    for (int dt = 0; dt < 3; ++dt)
#pragma unroll
      for (int ss = 0; ss < 2; ++ss)
#pragma unroll
        for (int q2 = 0; q2 < 2; ++q2)
          oacc[q2][dt] = __builtin_amdgcn_mfma_f32_32x32x16_f16(
              pa[q2][ss], Vb[dt * 2 + ss], oacc[q2][dt], 0, 0, 0);
  }

  if (kq == 0 && l < 32) LfinB[qh * 32 + l] = lreg;
  __syncthreads();

  // ---- epilogue: O/l, head max-pool (head = reg&3), store ----
  f32x4 rlv[2][4];
#pragma unroll
  for (int q2 = 0; q2 < 2; ++q2)
#pragma unroll
    for (int rr = 0; rr < 4; ++rr) {
      f32x4 lv = *(const f32x4*)(LfinB + q2 * 32 + rr * 8 + h * 4);
      rlv[q2][rr] =
          (f32x4){1.0f / lv[0], 1.0f / lv[1], 1.0f / lv[2], 1.0f / lv[3]};
    }
#pragma unroll
  for (int q2 = 0; q2 < 2; ++q2)
#pragma unroll
    for (int dt = 0; dt < 3; ++dt)
#pragma unroll
      for (int rr = 0; rr < 4; ++rr) {
        float mv = oacc[q2][dt][4 * rr + 0] * rlv[q2][rr][0];
        mv = fmaxf(mv, oacc[q2][dt][4 * rr + 1] * rlv[q2][rr][1]);
        mv = fmaxf(mv, oacc[q2][dt][4 * rr + 2] * rlv[q2][rr][2]);
        mv = fmaxf(mv, oacc[q2][dt][4 * rr + 3] * rlv[q2][rr][3]);
        int e_loc = q2 * 8 + rr * 2 + h;
        out_m[((size_t)b * E_ + e0 + e_loc) * D_ + dh * 96 + dt * 32 + l31] = mv;
      }
}

// ---------------------------------------------------------------------------
// logits[b,e] = sum_d cls_w[e,d]*m[b,e,d] + cls_b[e]; one wave per (b,e)
// ---------------------------------------------------------------------------
__global__ __launch_bounds__(256) void k_logits(const float* __restrict__ cw,
                                                const float* __restrict__ cb,
                                                const float* __restrict__ m,
                                                float* __restrict__ out) {
  int t = threadIdx.x, w = t >> 6, lane = t & 63;
  int rid = blockIdx.x * 4 + w;  // 0..7999
  int b = rid / E_, e = rid - b * E_;
  const float* mr = m + (size_t)rid * D_;
  const float* cr = cw + (size_t)e * D_;
  float acc = 0.f;
#pragma unroll
  for (int i = 0; i < 12; ++i) acc += cr[i * 64 + lane] * mr[i * 64 + lane];
#pragma unroll
  for (int off = 32; off >= 1; off >>= 1) acc += __shfl_xor(acc, off);
  if (lane == 0) out[rid] = acc + cb[e];
}

// ---------------------------------------------------------------------------
extern "C" void kernel_launch(void* const* d_in, const int* in_sizes, int n_in,
                              void* d_out, int out_size, void* d_ws, size_t ws_size,
                              hipStream_t stream) {
  const float* h = (const float*)d_in[0];
  const int* amask = (const int*)d_in[1];
  const float* lf = (const float*)d_in[2];
  const float* Ww = (const float*)d_in[3];
  const float* Wb = (const float*)d_in[4];
  const float* cw = (const float*)d_in[5];
  const float* cb = (const float*)d_in[6];
  float* out = (float*)d_out;

  f16* zb = (f16*)d_ws;                     // 12288*768*2 = 18874368 B
  f16* ht = (f16*)((char*)d_ws + 18874368); // 4*768*3072*2 = 18874368 B

  k_transpose<<<dim3(48, 12, 4), 256, 0, stream>>>(h, ht);
  k_zgemm<<<dim3(192, 12), 256, 0, stream>>>(h, Ww, Wb, zb);
  k_attn<<<512, 512, 0, stream>>>(lf, zb, ht, amask, out + 8000);
  k_logits<<<2000, 256, 0, stream>>>(cw, cb, out + 8000, out);
}